// Round 7
// baseline (97.227 us; speedup 1.0000x reference)
//
#include <hip/hip_runtime.h>
#include <math.h>

// LDDMM variational RHS, Gaussian kernel sigma=0.1, B=1, N=8192, D=3.
// out[0:N*3]     = dmom_i = (1/sig^2) * (x_i * sum_j W_ij - sum_j W_ij x_j)
// out[N*3:2*N*3] = dcp_i  = sum_j K_ij p_j
// K_ij = exp(-|x_i-x_j|^2/(2 sig^2)), W_ij = K_ij*(p_i.p_j), p=clamp(mom,-1,1)
//
// R7 model: R6 (packed fp32, 2 i/thread) dropped per-wave-iter VALU to 46 cy
// but the per-CU shared LDS pipe still sees 24 cy/wave-iter; at 16 waves/CU
// LDS demand (384 cy/CU-round) > VALU (184 cy/SIMD-round) -> LDS-bound,
// ~35us @1.4GHz ~= measured ~33. Fix: MI=4 v2f = 8 i-points/thread so one
// (xj,pj) LDS read feeds 512 pairs: 184 cy VALU vs 24 cy LDS per wave-iter
// -> VALU-bound. 4 i-blocks x 128 j-groups = 512 blocks, JLEN=64, ws 33.5MB.
// Predicted partial: 23.6k cy/SIMD = 9.8us @2.4GHz / 16.8us @1.4GHz.
// Harness's 268MB d_ws 0xAA re-poison (~43.5us fill) is a fixed tax.

#define NPTS 8192
#define N3   (NPTS * 3)
#define BI   256
#define MI   4                        // v2f groups per thread = 8 i-points
#define PPT  (MI * 2)                 // 8 i-points per thread
#define IBLK (NPTS / (BI * PPT))      // 4 i-blocks
#define JC   128                      // j-groups (= ws chunk rows)
#define JLEN (NPTS / JC)              // 64 j's per group

// exp(-d2/(2*0.1^2)) = exp2(d2 * (-50*log2(e)))
#define COEF    (-72.134752044448170f)
#define M2COEF  (144.269504088896340f)     // -2*COEF
#define UNSC100 (0.69314718055994531f)     // 100 / M2COEF

#define WS_NEEDED ((size_t)JC * NPTS * 8 * sizeof(float))  // 33.5 MB

typedef float v2f __attribute__((ext_vector_type(2)));

__device__ __forceinline__ v2f vsplat(float s) { v2f r; r.x = s; r.y = s; return r; }

__device__ __forceinline__ v2f pkfma(v2f a, v2f b, v2f c) {
#if __has_builtin(__builtin_elementwise_fma)
    return __builtin_elementwise_fma(a, b, c);
#else
    v2f r; r.x = fmaf(a.x, b.x, c.x); r.y = fmaf(a.y, b.y, c.y); return r;
#endif
}

__device__ __forceinline__ float fast_exp2(float x) {
#if __has_builtin(__builtin_amdgcn_exp2f)
    return __builtin_amdgcn_exp2f(x);
#else
    return exp2f(x);
#endif
}

__device__ __forceinline__ float clamp1(float v) {
    return fminf(fmaxf(v, -1.0f), 1.0f);
}

// ws layout: ws[((c*NPTS)+i)*8 + k], k=0..3: dcp0,dcp1,dcp2,wsum
//                                    k=4..7: wxs0,wxs1,wxs2,0 (wxs = M2COEF*wx)
__global__ __launch_bounds__(BI) void lddmm_partial(const float* __restrict__ mom,
                                                    const float* __restrict__ cp,
                                                    float* __restrict__ ws) {
    const int ib = (int)blockIdx.x / JC;
    const int jc = (int)blockIdx.x % JC;
    const int t  = (int)threadIdx.x;
    const int i0 = ib * (BI * PPT) + t;   // 8 i's per thread, stride BI
                                          // v2f m covers i0+2m*BI (.x), i0+(2m+1)*BI (.y)

    v2f xi0[MI], xi1[MI], xi2[MI], ci[MI], pi0[MI], pi1[MI], pi2[MI];
#pragma unroll
    for (int m = 0; m < MI; ++m) {
        const int ia = i0 + (2 * m) * BI;
        const int ib2 = i0 + (2 * m + 1) * BI;
        const float a0 = cp[ia * 3 + 0], a1 = cp[ia * 3 + 1], a2 = cp[ia * 3 + 2];
        const float b0 = cp[ib2 * 3 + 0], b1 = cp[ib2 * 3 + 1], b2 = cp[ib2 * 3 + 2];
        xi0[m].x = a0; xi0[m].y = b0;
        xi1[m].x = a1; xi1[m].y = b1;
        xi2[m].x = a2; xi2[m].y = b2;
        ci[m].x = COEF * (a0 * a0 + a1 * a1 + a2 * a2);
        ci[m].y = COEF * (b0 * b0 + b1 * b1 + b2 * b2);
        pi0[m].x = clamp1(mom[ia * 3 + 0]); pi0[m].y = clamp1(mom[ib2 * 3 + 0]);
        pi1[m].x = clamp1(mom[ia * 3 + 1]); pi1[m].y = clamp1(mom[ib2 * 3 + 1]);
        pi2[m].x = clamp1(mom[ia * 3 + 2]); pi2[m].y = clamp1(mom[ib2 * 3 + 2]);
    }

    // Stage j-group: shx = {M2COEF*xj, COEF*|xj|^2}, shp = {pj clamped, 0}
    __shared__ float4 shx[JLEN];
    __shared__ float4 shp[JLEN];
    if (t < JLEN) {
        const int j = jc * JLEN + t;
        const float x0 = cp[j * 3 + 0], x1 = cp[j * 3 + 1], x2 = cp[j * 3 + 2];
        shx[t] = make_float4(M2COEF * x0, M2COEF * x1, M2COEF * x2,
                             COEF * (x0 * x0 + x1 * x1 + x2 * x2));
        shp[t] = make_float4(clamp1(mom[j * 3 + 0]), clamp1(mom[j * 3 + 1]),
                             clamp1(mom[j * 3 + 2]), 0.0f);
    }
    __syncthreads();

    v2f dcp0[MI], dcp1[MI], dcp2[MI], wsum[MI], wx0[MI], wx1[MI], wx2[MI];
#pragma unroll
    for (int m = 0; m < MI; ++m) {
        dcp0[m] = vsplat(0.f); dcp1[m] = vsplat(0.f); dcp2[m] = vsplat(0.f);
        wsum[m] = vsplat(0.f);
        wx0[m] = vsplat(0.f); wx1[m] = vsplat(0.f); wx2[m] = vsplat(0.f);
    }

#pragma unroll 4
    for (int jj = 0; jj < JLEN; ++jj) {
        const float4 xj = shx[jj];   // wave-uniform -> LDS broadcast
        const float4 pj = shp[jj];
        const v2f sx0 = vsplat(xj.x), sx1 = vsplat(xj.y), sx2 = vsplat(xj.z);
        const v2f scj = vsplat(xj.w);
        const v2f sp0 = vsplat(pj.x), sp1 = vsplat(pj.y), sp2 = vsplat(pj.z);
#pragma unroll
        for (int m = 0; m < MI; ++m) {
            v2f arg = ci[m] + scj;               // 1 pk_add + 3 pk_fma
            arg = pkfma(xi2[m], sx2, arg);
            arg = pkfma(xi1[m], sx1, arg);
            arg = pkfma(xi0[m], sx0, arg);
            v2f K;                               // 2 trans
            K.x = fast_exp2(arg.x);
            K.y = fast_exp2(arg.y);
            v2f pd = pi0[m] * sp0;               // 1 pk_mul + 2 pk_fma
            pd = pkfma(pi1[m], sp1, pd);
            pd = pkfma(pi2[m], sp2, pd);
            const v2f W = K * pd;                // 1 pk_mul
            dcp0[m] = pkfma(K, sp0, dcp0[m]);    // 6 pk_fma + 1 pk_add
            dcp1[m] = pkfma(K, sp1, dcp1[m]);
            dcp2[m] = pkfma(K, sp2, dcp2[m]);
            wsum[m] = wsum[m] + W;
            wx0[m] = pkfma(W, sx0, wx0[m]);      // M2COEF-scaled
            wx1[m] = pkfma(W, sx1, wx1[m]);
            wx2[m] = pkfma(W, sx2, wx2[m]);
        }
    }

#pragma unroll
    for (int m = 0; m < MI; ++m) {
        const int ia = i0 + (2 * m) * BI;
        const int ib2 = i0 + (2 * m + 1) * BI;
        float4* oa = (float4*)(ws + ((size_t)(jc * NPTS) + ia) * 8);
        oa[0] = make_float4(dcp0[m].x, dcp1[m].x, dcp2[m].x, wsum[m].x);
        oa[1] = make_float4(wx0[m].x, wx1[m].x, wx2[m].x, 0.0f);
        float4* ob = (float4*)(ws + ((size_t)(jc * NPTS) + ib2) * 8);
        ob[0] = make_float4(dcp0[m].y, dcp1[m].y, dcp2[m].y, wsum[m].y);
        ob[1] = make_float4(wx0[m].y, wx1[m].y, wx2[m].y, 0.0f);
    }
}

// 4 threads per i: sub=(cpart,half). Each sums JC/2 chunks of one float4,
// xor-2 combines chunk halves, xor-1 hands wsum from half0 to half1.
// dmom = 100*xi*wsum - (100/M2COEF)*wxs.
__global__ __launch_bounds__(256) void lddmm_reduce(const float* __restrict__ ws,
                                                    const float* __restrict__ cp,
                                                    float* __restrict__ out) {
    const int tid   = (int)blockIdx.x * 256 + (int)threadIdx.x;
    const int i     = tid >> 2;
    const int sub   = tid & 3;
    const int half  = sub & 1;
    const int cpart = sub >> 1;

    float4 acc = make_float4(0.f, 0.f, 0.f, 0.f);
    const int c0 = cpart * (JC / 2);
#pragma unroll 4
    for (int c = c0; c < c0 + JC / 2; ++c) {
        const float4 v = ((const float4*)(ws + ((size_t)(c * NPTS) + i) * 8))[half];
        acc.x += v.x; acc.y += v.y; acc.z += v.z; acc.w += v.w;
    }
    acc.x += __shfl_xor(acc.x, 2);
    acc.y += __shfl_xor(acc.y, 2);
    acc.z += __shfl_xor(acc.z, 2);
    acc.w += __shfl_xor(acc.w, 2);
    const float wsum = __shfl_xor(acc.w, 1);
    if (sub == 0) {
        out[N3 + i * 3 + 0] = acc.x;
        out[N3 + i * 3 + 1] = acc.y;
        out[N3 + i * 3 + 2] = acc.z;
    } else if (sub == 1) {
        const float xi0 = cp[i * 3 + 0];
        const float xi1 = cp[i * 3 + 1];
        const float xi2 = cp[i * 3 + 2];
        out[i * 3 + 0] = fmaf(100.0f * xi0, wsum, -UNSC100 * acc.x);
        out[i * 3 + 1] = fmaf(100.0f * xi1, wsum, -UNSC100 * acc.y);
        out[i * 3 + 2] = fmaf(100.0f * xi2, wsum, -UNSC100 * acc.z);
    }
}

// ---- fallback (atomics into d_out) if ws_size < WS_NEEDED ----
#define FJC   32
#define FJLEN (NPTS / FJC)
__global__ __launch_bounds__(BI) void lddmm_pairs_atomic(const float* __restrict__ mom,
                                                         const float* __restrict__ cp,
                                                         float* __restrict__ out) {
    const int ib = (int)blockIdx.x / FJC;
    const int jc = (int)blockIdx.x % FJC;
    const int t  = (int)threadIdx.x;
    const int i  = ib * BI + t;

    const float xi0 = cp[i * 3 + 0], xi1 = cp[i * 3 + 1], xi2 = cp[i * 3 + 2];
    const float pi0 = clamp1(mom[i * 3 + 0]), pi1 = clamp1(mom[i * 3 + 1]),
                pi2 = clamp1(mom[i * 3 + 2]);

    __shared__ float4 shx[FJLEN];
    __shared__ float4 shp[FJLEN];
    {
        const int j = jc * FJLEN + t;
        shx[t] = make_float4(cp[j * 3 + 0], cp[j * 3 + 1], cp[j * 3 + 2], 0.0f);
        shp[t] = make_float4(clamp1(mom[j * 3 + 0]), clamp1(mom[j * 3 + 1]),
                             clamp1(mom[j * 3 + 2]), 0.0f);
    }
    __syncthreads();

    float dcp0 = 0.f, dcp1 = 0.f, dcp2 = 0.f, wsum = 0.f, wx0 = 0.f, wx1 = 0.f, wx2 = 0.f;
#pragma unroll 4
    for (int jj = 0; jj < FJLEN; ++jj) {
        const float4 xj = shx[jj];
        const float4 pj = shp[jj];
        const float dx0 = xi0 - xj.x, dx1 = xi1 - xj.y, dx2 = xi2 - xj.z;
        const float d2  = dx0 * dx0 + dx1 * dx1 + dx2 * dx2;
        const float K   = fast_exp2(d2 * COEF);
        const float pd  = pi0 * pj.x + pi1 * pj.y + pi2 * pj.z;
        const float W   = K * pd;
        dcp0 += K * pj.x; dcp1 += K * pj.y; dcp2 += K * pj.z;
        wsum += W;
        wx0 += W * xj.x; wx1 += W * xj.y; wx2 += W * xj.z;
    }
    atomicAdd(&out[i * 3 + 0], 100.0f * (xi0 * wsum - wx0));
    atomicAdd(&out[i * 3 + 1], 100.0f * (xi1 * wsum - wx1));
    atomicAdd(&out[i * 3 + 2], 100.0f * (xi2 * wsum - wx2));
    atomicAdd(&out[N3 + i * 3 + 0], dcp0);
    atomicAdd(&out[N3 + i * 3 + 1], dcp1);
    atomicAdd(&out[N3 + i * 3 + 2], dcp2);
}

extern "C" void kernel_launch(void* const* d_in, const int* in_sizes, int n_in,
                              void* d_out, int out_size, void* d_ws, size_t ws_size,
                              hipStream_t stream) {
    const float* mom = (const float*)d_in[0];
    const float* cp  = (const float*)d_in[1];
    float* out = (float*)d_out;

    if (ws_size >= WS_NEEDED) {
        float* ws = (float*)d_ws;
        hipLaunchKernelGGL(lddmm_partial, dim3(IBLK * JC), dim3(BI), 0, stream, mom, cp, ws);
        hipLaunchKernelGGL(lddmm_reduce, dim3(NPTS * 4 / 256), dim3(256), 0, stream, ws, cp, out);
    } else {
        hipMemsetAsync(out, 0, (size_t)out_size * sizeof(float), stream);
        hipLaunchKernelGGL(lddmm_pairs_atomic, dim3((NPTS / BI) * FJC), dim3(BI), 0, stream, mom, cp, out);
    }
}

// Round 8
// 96.068 us; speedup vs baseline: 1.0121x; 1.0121x over previous
//
#include <hip/hip_runtime.h>
#include <math.h>

// LDDMM variational RHS, Gaussian kernel sigma=0.1, B=1, N=8192, D=3.
// out[0:N*3]     = dmom_i = (1/sig^2) * (x_i * sum_j W_ij - sum_j W_ij x_j)
// out[N*3:2*N*3] = dcp_i  = sum_j K_ij p_j
// K_ij = exp(-|x_i-x_j|^2/(2 sig^2)), W_ij = K_ij*(p_i.p_j), p=clamp(mom,-1,1)
//
// R8 model (fits R2/R6/R7): time ~ max(VALU/SIMD, LDS-return/CU) at ~1.85GHz
// effective; each wave's 2x ds_read_b128 costs ~12cy on the shared per-CU
// LDS return bus even for broadcast. R6 (2 i/thr, 16 waves/CU): LDS 49k
// cy/CU = 26.5us ~= measured 33 (LDS-bound). R7 (8 i/thr, 2 waves/SIMD):
// latency-bound regression — too thin to hide exp/fma chains.
// R8 = midpoint: MI=2 v2f (4 i/thread), JC=128 -> 1024 blocks, 16 waves/CU
// (R6's occupancy) with half R6's LDS pressure: LDS 24.6k cy/CU = 13.3us,
// VALU 15.4k cy/SIMD = 8.3us, trans 16.4k = 8.9us -> partial ~18-22us.
// Harness's 256MiB d_ws 0xAA re-poison (~43.5us fill) is a fixed tax.

#define NPTS 8192
#define N3   (NPTS * 3)
#define BI   256
#define MI   2                        // v2f groups per thread = 4 i-points
#define PPT  (MI * 2)                 // 4 i-points per thread
#define IBLK (NPTS / (BI * PPT))      // 8 i-blocks
#define JC   128                      // j-chunks (= ws chunk rows)
#define JLEN (NPTS / JC)              // 64 j's per chunk

// exp(-d2/(2*0.1^2)) = exp2(d2 * (-50*log2(e)))
#define COEF    (-72.134752044448170f)
#define M2COEF  (144.269504088896340f)     // -2*COEF
#define UNSC100 (0.69314718055994531f)     // 100 / M2COEF

#define WS_NEEDED ((size_t)JC * NPTS * 8 * sizeof(float))  // 33.5 MB

typedef float v2f __attribute__((ext_vector_type(2)));

__device__ __forceinline__ v2f vsplat(float s) { v2f r; r.x = s; r.y = s; return r; }

__device__ __forceinline__ v2f pkfma(v2f a, v2f b, v2f c) {
#if __has_builtin(__builtin_elementwise_fma)
    return __builtin_elementwise_fma(a, b, c);
#else
    v2f r; r.x = fmaf(a.x, b.x, c.x); r.y = fmaf(a.y, b.y, c.y); return r;
#endif
}

__device__ __forceinline__ float fast_exp2(float x) {
#if __has_builtin(__builtin_amdgcn_exp2f)
    return __builtin_amdgcn_exp2f(x);
#else
    return exp2f(x);
#endif
}

__device__ __forceinline__ float clamp1(float v) {
    return fminf(fmaxf(v, -1.0f), 1.0f);
}

// ws layout: ws[((c*NPTS)+i)*8 + k], k=0..3: dcp0,dcp1,dcp2,wsum
//                                    k=4..7: wxs0,wxs1,wxs2,0 (wxs = M2COEF*wx)
__global__ __launch_bounds__(BI, 4) void lddmm_partial(const float* __restrict__ mom,
                                                       const float* __restrict__ cp,
                                                       float* __restrict__ ws) {
    const int ib = (int)blockIdx.x / JC;
    const int jc = (int)blockIdx.x % JC;
    const int t  = (int)threadIdx.x;
    const int i0 = ib * (BI * PPT) + t;   // 4 i's per thread, stride BI
                                          // v2f m covers i0+2m*BI (.x), i0+(2m+1)*BI (.y)

    v2f xi0[MI], xi1[MI], xi2[MI], ci[MI], pi0[MI], pi1[MI], pi2[MI];
#pragma unroll
    for (int m = 0; m < MI; ++m) {
        const int ia  = i0 + (2 * m) * BI;
        const int ib2 = i0 + (2 * m + 1) * BI;
        const float a0 = cp[ia * 3 + 0], a1 = cp[ia * 3 + 1], a2 = cp[ia * 3 + 2];
        const float b0 = cp[ib2 * 3 + 0], b1 = cp[ib2 * 3 + 1], b2 = cp[ib2 * 3 + 2];
        xi0[m].x = a0; xi0[m].y = b0;
        xi1[m].x = a1; xi1[m].y = b1;
        xi2[m].x = a2; xi2[m].y = b2;
        ci[m].x = COEF * (a0 * a0 + a1 * a1 + a2 * a2);
        ci[m].y = COEF * (b0 * b0 + b1 * b1 + b2 * b2);
        pi0[m].x = clamp1(mom[ia * 3 + 0]); pi0[m].y = clamp1(mom[ib2 * 3 + 0]);
        pi1[m].x = clamp1(mom[ia * 3 + 1]); pi1[m].y = clamp1(mom[ib2 * 3 + 1]);
        pi2[m].x = clamp1(mom[ia * 3 + 2]); pi2[m].y = clamp1(mom[ib2 * 3 + 2]);
    }

    // Stage j-chunk: shx = {M2COEF*xj, COEF*|xj|^2}, shp = {pj clamped, 0}
    __shared__ float4 shx[JLEN];
    __shared__ float4 shp[JLEN];
    if (t < JLEN) {
        const int j = jc * JLEN + t;
        const float x0 = cp[j * 3 + 0], x1 = cp[j * 3 + 1], x2 = cp[j * 3 + 2];
        shx[t] = make_float4(M2COEF * x0, M2COEF * x1, M2COEF * x2,
                             COEF * (x0 * x0 + x1 * x1 + x2 * x2));
        shp[t] = make_float4(clamp1(mom[j * 3 + 0]), clamp1(mom[j * 3 + 1]),
                             clamp1(mom[j * 3 + 2]), 0.0f);
    }
    __syncthreads();

    v2f dcp0[MI], dcp1[MI], dcp2[MI], wsum[MI], wx0[MI], wx1[MI], wx2[MI];
#pragma unroll
    for (int m = 0; m < MI; ++m) {
        dcp0[m] = vsplat(0.f); dcp1[m] = vsplat(0.f); dcp2[m] = vsplat(0.f);
        wsum[m] = vsplat(0.f);
        wx0[m] = vsplat(0.f); wx1[m] = vsplat(0.f); wx2[m] = vsplat(0.f);
    }

#pragma unroll 4
    for (int jj = 0; jj < JLEN; ++jj) {
        const float4 xj = shx[jj];   // wave-uniform -> LDS broadcast
        const float4 pj = shp[jj];
        const v2f sx0 = vsplat(xj.x), sx1 = vsplat(xj.y), sx2 = vsplat(xj.z);
        const v2f scj = vsplat(xj.w);
        const v2f sp0 = vsplat(pj.x), sp1 = vsplat(pj.y), sp2 = vsplat(pj.z);
#pragma unroll
        for (int m = 0; m < MI; ++m) {
            v2f arg = ci[m] + scj;               // 1 pk_add + 3 pk_fma
            arg = pkfma(xi2[m], sx2, arg);
            arg = pkfma(xi1[m], sx1, arg);
            arg = pkfma(xi0[m], sx0, arg);
            v2f K;                               // 2 trans
            K.x = fast_exp2(arg.x);
            K.y = fast_exp2(arg.y);
            v2f pd = pi0[m] * sp0;               // 1 pk_mul + 2 pk_fma
            pd = pkfma(pi1[m], sp1, pd);
            pd = pkfma(pi2[m], sp2, pd);
            const v2f W = K * pd;                // 1 pk_mul
            dcp0[m] = pkfma(K, sp0, dcp0[m]);    // 6 pk_fma + 1 pk_add
            dcp1[m] = pkfma(K, sp1, dcp1[m]);
            dcp2[m] = pkfma(K, sp2, dcp2[m]);
            wsum[m] = wsum[m] + W;
            wx0[m] = pkfma(W, sx0, wx0[m]);      // M2COEF-scaled
            wx1[m] = pkfma(W, sx1, wx1[m]);
            wx2[m] = pkfma(W, sx2, wx2[m]);
        }
    }

#pragma unroll
    for (int m = 0; m < MI; ++m) {
        const int ia  = i0 + (2 * m) * BI;
        const int ib2 = i0 + (2 * m + 1) * BI;
        float4* oa = (float4*)(ws + ((size_t)(jc * NPTS) + ia) * 8);
        oa[0] = make_float4(dcp0[m].x, dcp1[m].x, dcp2[m].x, wsum[m].x);
        oa[1] = make_float4(wx0[m].x, wx1[m].x, wx2[m].x, 0.0f);
        float4* ob = (float4*)(ws + ((size_t)(jc * NPTS) + ib2) * 8);
        ob[0] = make_float4(dcp0[m].y, dcp1[m].y, dcp2[m].y, wsum[m].y);
        ob[1] = make_float4(wx0[m].y, wx1[m].y, wx2[m].y, 0.0f);
    }
}

// 4 threads per i: sub=(cpart,half). Each sums JC/2 chunks of one float4,
// xor-2 combines chunk halves, xor-1 hands wsum from half0 to half1.
// dmom = 100*xi*wsum - (100/M2COEF)*wxs.
__global__ __launch_bounds__(256) void lddmm_reduce(const float* __restrict__ ws,
                                                    const float* __restrict__ cp,
                                                    float* __restrict__ out) {
    const int tid   = (int)blockIdx.x * 256 + (int)threadIdx.x;
    const int i     = tid >> 2;
    const int sub   = tid & 3;
    const int half  = sub & 1;
    const int cpart = sub >> 1;

    float4 acc = make_float4(0.f, 0.f, 0.f, 0.f);
    const int c0 = cpart * (JC / 2);
#pragma unroll 4
    for (int c = c0; c < c0 + JC / 2; ++c) {
        const float4 v = ((const float4*)(ws + ((size_t)(c * NPTS) + i) * 8))[half];
        acc.x += v.x; acc.y += v.y; acc.z += v.z; acc.w += v.w;
    }
    acc.x += __shfl_xor(acc.x, 2);
    acc.y += __shfl_xor(acc.y, 2);
    acc.z += __shfl_xor(acc.z, 2);
    acc.w += __shfl_xor(acc.w, 2);
    const float wsum = __shfl_xor(acc.w, 1);
    if (sub == 0) {
        out[N3 + i * 3 + 0] = acc.x;
        out[N3 + i * 3 + 1] = acc.y;
        out[N3 + i * 3 + 2] = acc.z;
    } else if (sub == 1) {
        const float xi0 = cp[i * 3 + 0];
        const float xi1 = cp[i * 3 + 1];
        const float xi2 = cp[i * 3 + 2];
        out[i * 3 + 0] = fmaf(100.0f * xi0, wsum, -UNSC100 * acc.x);
        out[i * 3 + 1] = fmaf(100.0f * xi1, wsum, -UNSC100 * acc.y);
        out[i * 3 + 2] = fmaf(100.0f * xi2, wsum, -UNSC100 * acc.z);
    }
}

// ---- fallback (atomics into d_out) if ws_size < WS_NEEDED ----
#define FJC   32
#define FJLEN (NPTS / FJC)
__global__ __launch_bounds__(BI) void lddmm_pairs_atomic(const float* __restrict__ mom,
                                                         const float* __restrict__ cp,
                                                         float* __restrict__ out) {
    const int ib = (int)blockIdx.x / FJC;
    const int jc = (int)blockIdx.x % FJC;
    const int t  = (int)threadIdx.x;
    const int i  = ib * BI + t;

    const float xi0 = cp[i * 3 + 0], xi1 = cp[i * 3 + 1], xi2 = cp[i * 3 + 2];
    const float pi0 = clamp1(mom[i * 3 + 0]), pi1 = clamp1(mom[i * 3 + 1]),
                pi2 = clamp1(mom[i * 3 + 2]);

    __shared__ float4 shx[FJLEN];
    __shared__ float4 shp[FJLEN];
    {
        const int j = jc * FJLEN + t;
        shx[t] = make_float4(cp[j * 3 + 0], cp[j * 3 + 1], cp[j * 3 + 2], 0.0f);
        shp[t] = make_float4(clamp1(mom[j * 3 + 0]), clamp1(mom[j * 3 + 1]),
                             clamp1(mom[j * 3 + 2]), 0.0f);
    }
    __syncthreads();

    float dcp0 = 0.f, dcp1 = 0.f, dcp2 = 0.f, wsum = 0.f, wx0 = 0.f, wx1 = 0.f, wx2 = 0.f;
#pragma unroll 4
    for (int jj = 0; jj < FJLEN; ++jj) {
        const float4 xj = shx[jj];
        const float4 pj = shp[jj];
        const float dx0 = xi0 - xj.x, dx1 = xi1 - xj.y, dx2 = xi2 - xj.z;
        const float d2  = dx0 * dx0 + dx1 * dx1 + dx2 * dx2;
        const float K   = fast_exp2(d2 * COEF);
        const float pd  = pi0 * pj.x + pi1 * pj.y + pi2 * pj.z;
        const float W   = K * pd;
        dcp0 += K * pj.x; dcp1 += K * pj.y; dcp2 += K * pj.z;
        wsum += W;
        wx0 += W * xj.x; wx1 += W * xj.y; wx2 += W * xj.z;
    }
    atomicAdd(&out[i * 3 + 0], 100.0f * (xi0 * wsum - wx0));
    atomicAdd(&out[i * 3 + 1], 100.0f * (xi1 * wsum - wx1));
    atomicAdd(&out[i * 3 + 2], 100.0f * (xi2 * wsum - wx2));
    atomicAdd(&out[N3 + i * 3 + 0], dcp0);
    atomicAdd(&out[N3 + i * 3 + 1], dcp1);
    atomicAdd(&out[N3 + i * 3 + 2], dcp2);
}

extern "C" void kernel_launch(void* const* d_in, const int* in_sizes, int n_in,
                              void* d_out, int out_size, void* d_ws, size_t ws_size,
                              hipStream_t stream) {
    const float* mom = (const float*)d_in[0];
    const float* cp  = (const float*)d_in[1];
    float* out = (float*)d_out;

    if (ws_size >= WS_NEEDED) {
        float* ws = (float*)d_ws;
        hipLaunchKernelGGL(lddmm_partial, dim3(IBLK * JC), dim3(BI), 0, stream, mom, cp, ws);
        hipLaunchKernelGGL(lddmm_reduce, dim3(NPTS * 4 / 256), dim3(256), 0, stream, ws, cp, out);
    } else {
        hipMemsetAsync(out, 0, (size_t)out_size * sizeof(float), stream);
        hipLaunchKernelGGL(lddmm_pairs_atomic, dim3((NPTS / BI) * FJC), dim3(BI), 0, stream, mom, cp, out);
    }
}